// Round 16
// baseline (74.258 us; speedup 1.0000x reference)
//
#include <hip/hip_runtime.h>

#define N_NODES 98304
#define N_EDGES 1572864
#define HIDDEN  64

#define NB      1536     // buckets of 64 nodes; bucket = dst >> 6
#define NBLK    1536     // chunks; CHUNK*NBLK == N_EDGES
#define CHUNK   1024     // edges per chunk (private payload region per block)
#define TPB     256
#define EPT     4        // 256*4 = 1024
#define NBXC    (NB / 8) // buckets per XCD = 192

#define FP_SCALE 1048576.0f          // 2^20
#define FP_INV   (1.0f / 1048576.0f)

__device__ __forceinline__ float silu_f(float x) {
    return x / (1.0f + __expf(-x));
}

// ---- kernel 1: private-chunk LDS counting sort (fine buckets) ----
// payload u64: [63:37]=dr(27b) [36:10]=di(27b) [9:4]=local node(6b) [1]=inter flag
// Block sorts its 1024-edge chunk by bucket in LDS, writes it LINEARLY to its
// private payload region (fully coalesced, NO device atomics), and emits
// per-bucket start offsets lbT[chunk][bucket] (u16, linear write).
__global__ __launch_bounds__(TPB) void k_scatter(const int* __restrict__ ei,
    const float* __restrict__ ew, const float* __restrict__ xr,
    const float* __restrict__ xi, const int* __restrict__ comm,
    unsigned short* __restrict__ lbT, unsigned long long* __restrict__ payload)
{
    __shared__ unsigned long long sorted[CHUNK];   // 8 KB
    __shared__ unsigned hist[NB];                  // 6 KB
    __shared__ unsigned localbase[NB];             // 6 KB

    const int tid = threadIdx.x, blk = blockIdx.x;
    for (int i = tid; i < NB; i += TPB) hist[i] = 0;
    __syncthreads();

    const int ebase = blk * CHUNK;
    unsigned long long pay[EPT];
    unsigned pb[EPT], pr[EPT];
#pragma unroll
    for (int k = 0; k < EPT; ++k) {
        const int e = ebase + k * TPB + tid;
        const int s = __builtin_nontemporal_load(&ei[e]);
        const int d = __builtin_nontemporal_load(&ei[N_EDGES + e]);
        const float w = __builtin_nontemporal_load(&ew[e]);
        const int dr = __float2int_rn(w * xr[s] * FP_SCALE);
        const int di = __float2int_rn(w * xi[s] * FP_SCALE);
        const unsigned flag = (comm[s] == comm[d]) ? 0u : 1u;
        const unsigned b = (unsigned)d >> 6;
        pb[k] = b;
        pr[k] = atomicAdd(&hist[b], 1u);
        pay[k] = ((unsigned long long)((unsigned)dr & 0x07FFFFFFu) << 37)
               | ((unsigned long long)((unsigned)di & 0x07FFFFFFu) << 10)
               | ((unsigned long long)((unsigned)(d & 63)) << 4)
               | ((unsigned long long)flag << 1);
    }
    __syncthreads();

    if (tid < 64) {   // wave 0: exclusive scan of 1536 counts, 24 per lane
        unsigned v[24];
        unsigned s = 0;
#pragma unroll
        for (int m = 0; m < 24; ++m) { v[m] = hist[tid * 24 + m]; s += v[m]; }
        unsigned p = s;
#pragma unroll
        for (int off = 1; off < 64; off <<= 1) {
            unsigned t = __shfl_up(p, off);
            if (tid >= off) p += t;
        }
        unsigned excl = p - s;
#pragma unroll
        for (int m = 0; m < 24; ++m) { unsigned t = v[m]; localbase[tid * 24 + m] = excl; excl += t; }
    }
    __syncthreads();

#pragma unroll
    for (int k = 0; k < EPT; ++k)
        sorted[localbase[pb[k]] + pr[k]] = pay[k];
    for (int i = tid; i < NB; i += TPB)
        lbT[(size_t)blk * NB + i] = (unsigned short)localbase[i];
    __syncthreads();

    // vectorized linear copyout (16 B per lane)
    const ulonglong2* src2 = (const ulonglong2*)sorted;
    ulonglong2* dst2 = (ulonglong2*)(payload + (size_t)blk * CHUNK);
#pragma unroll
    for (int i = tid; i < CHUNK / 2; i += TPB)
        dst2[i] = src2[i];
}

// ---- kernel 2: transpose + pack offsets ----
// lbT[chunk][bucket] (start only) -> lbTT[bucket][chunk] u16 = start<<6 | min(cnt,63)
// 64x64 tiles via LDS; both global sides coalesced.
__global__ __launch_bounds__(TPB) void k_transpose(
    const unsigned short* __restrict__ lbT,
    unsigned short* __restrict__ lbTT)
{
    __shared__ unsigned short t[64][66];   // 64 chunks x 65 buckets (+pad)
    const int b0 = blockIdx.x * 64;        // bucket tile origin
    const int c0 = blockIdx.y * 64;        // chunk tile origin
    const int tid = threadIdx.x;

    for (int idx = tid; idx < 64 * 65; idx += TPB) {
        const int r  = idx / 65;           // chunk row
        const int cb = idx % 65;           // bucket col (need +1 for count)
        const int gb = b0 + cb;
        t[r][cb] = (gb < NB) ? lbT[(size_t)(c0 + r) * NB + gb]
                             : (unsigned short)CHUNK;
    }
    __syncthreads();

    for (int idx = tid; idx < 64 * 64; idx += TPB) {
        const int col = idx >> 6;          // bucket within tile
        const int r   = idx & 63;          // chunk within tile (consecutive tid -> coalesced)
        const unsigned start = t[r][col];
        unsigned cnt = (unsigned)t[r][col + 1] - start;
        if (cnt > 63u) cnt = 63u;          // saturation marker (accum falls back to lbT)
        const unsigned pk = cnt ? ((start << 6) | cnt) : 0u;
        lbTT[(size_t)(b0 + col) * NBLK + (c0 + r)] = (unsigned short)pk;
    }
}

// ---- kernel 3: fused accumulate + epilogue, one block per 64-node bucket ----
// Metadata read is LINEAR (3 KB/block); each payload entry visited exactly
// once grid-wide; XCD swizzle keeps neighbor buckets (sharing payload
// sectors) on one XCD -> local-L2 hits.
__global__ __launch_bounds__(TPB) void k_accum_final(
    const unsigned long long* __restrict__ payload,
    const unsigned short* __restrict__ lbTT,
    const unsigned short* __restrict__ lbT,
    const float* __restrict__ Wlr, const float* __restrict__ Wli,
    const float* __restrict__ Wgr, const float* __restrict__ Wgi,
    float4* __restrict__ out)
{
    __shared__ int accR[128];   // [64 local nodes][intra/inter]
    __shared__ int accI[128];
    __shared__ float2 w_s[4][32];
    const int tid = threadIdx.x, blk = blockIdx.x;
    const int bucket = (blk & 7) * NBXC + (blk >> 3);   // adjacent buckets same XCD

    if (tid < 128) { accR[tid] = 0; accI[tid] = 0; }
    else {
        const int t = tid - 128;
        const int which = t >> 5, h2 = t & 31;
        const float* W = (which == 0) ? Wlr : (which == 1) ? Wli
                       : (which == 2) ? Wgr : Wgi;
        w_s[which][h2] = ((const float2*)W)[h2];
    }
    __syncthreads();

    const unsigned short* row = lbTT + (size_t)bucket * NBLK;
    for (int c = tid; c < NBLK; c += TPB) {       // coalesced u16 row read
        const unsigned pk = row[c];
        if (pk == 0u) continue;
        const unsigned start = pk >> 6;
        unsigned end = start + (pk & 63u);
        if ((pk & 63u) == 63u) {                  // saturated: exact end from lbT
            end = (bucket < NB - 1)
                ? (unsigned)lbT[(size_t)c * NB + bucket + 1]
                : (unsigned)CHUNK;
        }
        const unsigned long long* chunkp = payload + (size_t)c * CHUNK;
        for (unsigned i = start; i < end; ++i) {
            const unsigned long long p = chunkp[i];
            const int dr = (int)((long long)p >> 37);
            const int di = (int)(((long long)(p << 27)) >> 37);
            const unsigned idx = (((unsigned)(p >> 4) & 63u) << 1) | ((unsigned)(p >> 1) & 1u);
            atomicAdd(&accR[idx], dr);
            atomicAdd(&accI[idx], di);
        }
    }
    __syncthreads();

    const size_t obase = (size_t)bucket * 2048;
#pragma unroll
    for (int jj = 0; jj < 8; ++jj) {
        const int idx = jj * 256 + tid;   // 0..2047 = local node(0..63)*32 + h2
        const int ln  = idx >> 5;
        const int h2  = idx & 31;
        const float sr_l = (float)accR[ln * 2 + 0] * FP_INV;
        const float si_l = (float)accI[ln * 2 + 0] * FP_INV;
        const float sr_g = (float)accR[ln * 2 + 1] * FP_INV;
        const float si_g = (float)accI[ln * 2 + 1] * FP_INV;
        const float2 a = w_s[0][h2], c = w_s[1][h2];
        const float2 g = w_s[2][h2], f = w_s[3][h2];
        float4 o;
        {
            const float arl = a.x * sr_l - c.x * si_l;
            const float ail = c.x * sr_l + a.x * si_l;
            const float arg = g.x * sr_g - f.x * si_g;
            const float aig = f.x * sr_g + g.x * si_g;
            o.x = silu_f(arl) + silu_f(arg);
            o.y = silu_f(ail) + silu_f(aig);
        }
        {
            const float arl = a.y * sr_l - c.y * si_l;
            const float ail = c.y * sr_l + a.y * si_l;
            const float arg = g.y * sr_g - f.y * si_g;
            const float aig = f.y * sr_g + g.y * si_g;
            o.z = silu_f(arl) + silu_f(arg);
            o.w = silu_f(ail) + silu_f(aig);
        }
        out[obase + idx] = o;
    }
}

// ---------------- minimal fallback (ws too small; never expected) ----------------
__global__ void edge_scatter_fb(const int* __restrict__ ei,
                                const float* __restrict__ ew,
                                const int* __restrict__ comm,
                                const float* __restrict__ xr,
                                const float* __restrict__ xi,
                                unsigned long long* __restrict__ P)
{
    const int e = blockIdx.x * blockDim.x + threadIdx.x;
    if (e >= N_EDGES) return;
    const int s = ei[e];
    const int d = ei[N_EDGES + e];
    const float w = ew[e];
    const int dr = __float2int_rn(w * xr[s] * FP_SCALE);
    const int di = __float2int_rn(w * xi[s] * FP_SCALE);
    const unsigned long long delta =
        (unsigned long long)(((long long)dr << 32) + (long long)di);
    const int base = (comm[s] == comm[d]) ? 0 : N_NODES;
    atomicAdd(&P[base + d], delta);
}

__global__ void epilogue_fb(const unsigned long long* __restrict__ P,
                            const float* __restrict__ Wlr,
                            const float* __restrict__ Wli,
                            const float* __restrict__ Wgr,
                            const float* __restrict__ Wgi,
                            float4* __restrict__ out)
{
    const int total = N_NODES * (HIDDEN / 2);
    const int t = blockIdx.x * blockDim.x + threadIdx.x;
    if (t >= total) return;
    const int n = t >> 5, h2 = t & 31;
    float sr_l, si_l, sr_g, si_g;
    {
        const unsigned long long U = P[n];
        const int bi = (int)(unsigned)(U & 0xffffffffULL);
        const int ar = (int)(unsigned)(U >> 32) + (bi < 0 ? 1 : 0);
        sr_l = (float)ar * FP_INV; si_l = (float)bi * FP_INV;
    }
    {
        const unsigned long long U = P[N_NODES + n];
        const int bi = (int)(unsigned)(U & 0xffffffffULL);
        const int ar = (int)(unsigned)(U >> 32) + (bi < 0 ? 1 : 0);
        sr_g = (float)ar * FP_INV; si_g = (float)bi * FP_INV;
    }
    const float2 wlr = ((const float2*)Wlr)[h2];
    const float2 wli = ((const float2*)Wli)[h2];
    const float2 wgr = ((const float2*)Wgr)[h2];
    const float2 wgi = ((const float2*)Wgi)[h2];
    float4 o;
    {
        const float arl = wlr.x * sr_l - wli.x * si_l;
        const float ail = wli.x * sr_l + wlr.x * si_l;
        const float arg = wgr.x * sr_g - wgi.x * si_g;
        const float aig = wgi.x * sr_g + wgr.x * si_g;
        o.x = silu_f(arl) + silu_f(arg);
        o.y = silu_f(ail) + silu_f(aig);
    }
    {
        const float arl = wlr.y * sr_l - wli.y * si_l;
        const float ail = wli.y * sr_l + wlr.y * si_l;
        const float arg = wgr.y * sr_g - wgi.y * si_g;
        const float aig = wgi.y * sr_g + wgr.y * si_g;
        o.z = silu_f(arl) + silu_f(arg);
        o.w = silu_f(ail) + silu_f(aig);
    }
    out[t] = o;
}

extern "C" void kernel_launch(void* const* d_in, const int* in_sizes, int n_in,
                              void* d_out, int out_size, void* d_ws, size_t ws_size,
                              hipStream_t stream) {
    const float* xr   = (const float*)d_in[0];
    const float* xi   = (const float*)d_in[1];
    const int*   ei   = (const int*)d_in[2];
    const float* ew   = (const float*)d_in[3];
    const int*   comm = (const int*)d_in[4];
    const float* Wlr  = (const float*)d_in[5];
    const float* Wli  = (const float*)d_in[6];
    const float* Wgr  = (const float*)d_in[7];
    const float* Wgi  = (const float*)d_in[8];

    const size_t payload_bytes = (size_t)N_EDGES * sizeof(unsigned long long);   // 12.58 MB
    const size_t lbT_bytes     = (size_t)NBLK * NB * sizeof(unsigned short);     // 4.72 MB
    const size_t lbTT_bytes    = (size_t)NB * NBLK * sizeof(unsigned short);     // 4.72 MB
    const size_t need = payload_bytes + lbT_bytes + lbTT_bytes;                  // ~22.02 MB

    if (ws_size >= need) {
        char* p = (char*)d_ws;
        unsigned long long* payload = (unsigned long long*)p;  p += payload_bytes;
        unsigned short* lbT         = (unsigned short*)p;      p += lbT_bytes;
        unsigned short* lbTT        = (unsigned short*)p;

        hipLaunchKernelGGL(k_scatter, dim3(NBLK), dim3(TPB), 0, stream,
                           ei, ew, xr, xi, comm, lbT, payload);
        hipLaunchKernelGGL(k_transpose, dim3(NB / 64, NBLK / 64), dim3(TPB), 0, stream,
                           lbT, lbTT);
        hipLaunchKernelGGL(k_accum_final, dim3(NB), dim3(TPB), 0, stream,
                           payload, lbTT, lbT, Wlr, Wli, Wgr, Wgi, (float4*)d_out);
    } else {
        unsigned long long* P = (unsigned long long*)d_ws;
        hipMemsetAsync(P, 0, (size_t)2 * N_NODES * sizeof(unsigned long long), stream);
        hipLaunchKernelGGL(edge_scatter_fb, dim3((N_EDGES + 255) / 256), dim3(256), 0, stream,
                           ei, ew, comm, xr, xi, P);
        const int total = N_NODES * (HIDDEN / 2);
        hipLaunchKernelGGL(epilogue_fb, dim3((total + 255) / 256), dim3(256), 0, stream,
                           P, Wlr, Wli, Wgr, Wgi, (float4*)d_out);
    }
}